// Round 1
// baseline (1652.452 us; speedup 1.0000x reference)
//
#include <hip/hip_runtime.h>
#include <math.h>

#define NV 4
#define NPT 65536
#define NC 128
#define IMH 512
#define IMW 512
#define MPOOL 1024
#define NDH 128
#define KNN 5
#define NB 4
#define OUTC 131

// ---------------------------------------------------------------------------
// Kernel A: project points into each view + bilinear sample zbuffer
// ---------------------------------------------------------------------------
__global__ void k_project(const float* __restrict__ pts,
                          const float* __restrict__ extr,
                          const float* __restrict__ intr,
                          const float* __restrict__ zbuffer,
                          float* __restrict__ uarr, float* __restrict__ varr,
                          float* __restrict__ darr, float* __restrict__ zarr) {
    int idx = blockIdx.x * blockDim.x + threadIdx.x;
    if (idx >= NV * NPT) return;
    int v = idx >> 16;          // NPT = 65536
    int n = idx & (NPT - 1);
    float p0 = pts[3 * n], p1 = pts[3 * n + 1], p2 = pts[3 * n + 2];
    const float* e = extr + v * 12;
    float c0 = e[0] * p0 + e[1] * p1 + e[2] * p2 + e[3];
    float c1 = e[4] * p0 + e[5] * p1 + e[6] * p2 + e[7];
    float c2 = e[8] * p0 + e[9] * p1 + e[10] * p2 + e[11];
    const float* kk = intr + v * 9;
    float x0 = kk[0] * c0 + kk[1] * c1 + kk[2] * c2;
    float x1 = kk[3] * c0 + kk[4] * c1 + kk[5] * c2;
    float x2 = kk[6] * c0 + kk[7] * c1 + kk[8] * c2;
    float uu = x0 / (x2 + 1e-9f);
    float vv = x1 / (x2 + 1e-9f);
    uarr[idx] = uu;
    varr[idx] = vv;
    darr[idx] = c2;

    // bilinear sample of zbuffer plane v (zero-padded out of bounds)
    const float* img = zbuffer + (size_t)v * IMH * IMW;
    float u0f = floorf(uu), v0f = floorf(vv);
    float du = uu - u0f, dv = vv - v0f;
    int iu0 = (int)u0f, iv0 = (int)v0f;
    float w00 = (1.f - du) * (1.f - dv);
    float w01 = du * (1.f - dv);
    float w10 = (1.f - du) * dv;
    float w11 = du * dv;
    int iu0c = min(max(iu0, 0), IMW - 1), iu1c = min(max(iu0 + 1, 0), IMW - 1);
    int iv0c = min(max(iv0, 0), IMH - 1), iv1c = min(max(iv0 + 1, 0), IMH - 1);
    float m00 = (iu0 >= 0 && iu0 < IMW && iv0 >= 0 && iv0 < IMH) ? w00 : 0.f;
    float m01 = (iu0 + 1 >= 0 && iu0 + 1 < IMW && iv0 >= 0 && iv0 < IMH) ? w01 : 0.f;
    float m10 = (iu0 >= 0 && iu0 < IMW && iv0 + 1 >= 0 && iv0 + 1 < IMH) ? w10 : 0.f;
    float m11 = (iu0 + 1 >= 0 && iu0 + 1 < IMW && iv0 + 1 >= 0 && iv0 + 1 < IMH) ? w11 : 0.f;
    float z = img[iv0c * IMW + iu0c] * m00 + img[iv0c * IMW + iu1c] * m01 +
              img[iv1c * IMW + iu0c] * m10 + img[iv1c * IMW + iu1c] * m11;
    zarr[idx] = z;
}

// ---------------------------------------------------------------------------
// Kernel B: out_mask[n] = any_v (zbuf[v][n] == 0)
// ---------------------------------------------------------------------------
__global__ void k_mask(const float* __restrict__ zarr, int* __restrict__ mask) {
    int n = blockIdx.x * blockDim.x + threadIdx.x;
    if (n >= NPT) return;
    int m = 0;
#pragma unroll
    for (int v = 0; v < NV; ++v) m |= (zarr[v * NPT + n] == 0.f);
    mask[n] = m;
}

// ---------------------------------------------------------------------------
// Kernel C: for masked points, top-5 NN among first MPOOL good candidates,
// inverse-distance weighted z replacement (in place; only good cands read).
// ---------------------------------------------------------------------------
__global__ void k_knn(const float* __restrict__ pts, const int* __restrict__ mask,
                      float* __restrict__ zarr) {
    int n = blockIdx.x * blockDim.x + threadIdx.x;
    if (n >= NPT) return;
    if (!mask[n]) return;
    float px = pts[3 * n], py = pts[3 * n + 1], pz = pts[3 * n + 2];
    float bd[KNN];
    int bi[KNN];
#pragma unroll
    for (int k = 0; k < KNN; ++k) { bd[k] = INFINITY; bi[k] = 0; }
    for (int m = 0; m < MPOOL; ++m) {
        float dx = px - pts[3 * m];
        float dy = py - pts[3 * m + 1];
        float dz = pz - pts[3 * m + 2];
        float d2 = dx * dx + dy * dy + dz * dz;
        if (mask[m]) d2 = INFINITY;
        float d = d2;
        int id = m;
#pragma unroll
        for (int k = 0; k < KNN; ++k) {
            // strict < : ties keep the earlier (lower) index, matching jax top_k
            if (d < bd[k]) {
                float td = bd[k]; int ti = bi[k];
                bd[k] = d; bi[k] = id;
                d = td; id = ti;
            }
        }
    }
    float disp[KNN];
    float s = 0.f;
#pragma unroll
    for (int k = 0; k < KNN; ++k) {
        float dist = sqrtf(fmaxf(bd[k], 0.f));   // sqrt(inf)=inf -> disp 0
        disp[k] = 1.f / (dist + 1e-8f);
        s += disp[k];
    }
    float inv = 1.f / (s + 1e-12f);
#pragma unroll
    for (int v = 0; v < NV; ++v) {
        float r = 0.f;
#pragma unroll
        for (int k = 0; k < KNN; ++k) r += zarr[v * NPT + bi[k]] * (disp[k] * inv);
        zarr[v * NPT + n] = r;
    }
}

// ---------------------------------------------------------------------------
// Kernel D: fused feature/RGB sampling + MLP + view softmax + blend.
// One 128-thread block handles NB=4 points across all 4 views.
// thread == channel for sampling / MLP output dim.
// ---------------------------------------------------------------------------
__global__ __launch_bounds__(128)
void k_fused(const float* __restrict__ uarr, const float* __restrict__ varr,
             const float* __restrict__ darr, const float* __restrict__ zarr,
             const float* __restrict__ feat, const float* __restrict__ image,
             const float* __restrict__ W1, const float* __restrict__ b1,
             const float* __restrict__ w2, float* __restrict__ out) {
    const int tid = threadIdx.x;
    const int n0 = blockIdx.x * NB;
    __shared__ float fs[NB][NV][NC];
    __shared__ float rgbs[NB][NV][3];
    __shared__ float sc[NB][NV];
    __shared__ float red[NB][NV][2];
    float vis[NB][NV];

#pragma unroll
    for (int nb = 0; nb < NB; ++nb) {
        int n = n0 + nb;
#pragma unroll
        for (int v = 0; v < NV; ++v) {
            int vn = v * NPT + n;
            float uu = uarr[vn], vv = varr[vn];
            float u0f = floorf(uu), v0f = floorf(vv);
            float du = uu - u0f, dv = vv - v0f;
            int iu0 = (int)u0f, iv0 = (int)v0f;
            float w00 = (1.f - du) * (1.f - dv);
            float w01 = du * (1.f - dv);
            float w10 = (1.f - du) * dv;
            float w11 = du * dv;
            int iu0c = min(max(iu0, 0), IMW - 1), iu1c = min(max(iu0 + 1, 0), IMW - 1);
            int iv0c = min(max(iv0, 0), IMH - 1), iv1c = min(max(iv0 + 1, 0), IMH - 1);
            float m00 = (iu0 >= 0 && iu0 < IMW && iv0 >= 0 && iv0 < IMH) ? w00 : 0.f;
            float m01 = (iu0 + 1 < IMW && iu0 + 1 >= 0 && iv0 >= 0 && iv0 < IMH) ? w01 : 0.f;
            float m10 = (iu0 >= 0 && iu0 < IMW && iv0 + 1 < IMH && iv0 + 1 >= 0) ? w10 : 0.f;
            float m11 = (iu0 + 1 < IMW && iu0 + 1 >= 0 && iv0 + 1 < IMH && iv0 + 1 >= 0) ? w11 : 0.f;
            int o00 = iv0c * IMW + iu0c, o01 = iv0c * IMW + iu1c;
            int o10 = iv1c * IMW + iu0c, o11 = iv1c * IMW + iu1c;

            const float* base = feat + ((size_t)(v * NC + tid)) * IMH * IMW;
            fs[nb][v][tid] = base[o00] * m00 + base[o01] * m01 +
                             base[o10] * m10 + base[o11] * m11;
            if (tid < 3) {
                const float* ib = image + ((size_t)(v * 3 + tid)) * IMH * IMW;
                rgbs[nb][v][tid] = ib[o00] * m00 + ib[o01] * m01 +
                                   ib[o10] * m10 + ib[o11] * m11;
            }
            float z = zarr[vn], dd = darr[vn];
            vis[nb][v] = 1.f - fabsf(z - dd) / (z + 1e-9f);
        }
    }
    __syncthreads();

    // MLP: h[d=tid] for 16 (nb,v) pairs; c-loop outer so one W1 read feeds 16 FMAs
    float h[NB][NV];
    float bv = b1[tid];
#pragma unroll
    for (int nb = 0; nb < NB; ++nb)
#pragma unroll
        for (int v = 0; v < NV; ++v) h[nb][v] = bv;

    for (int c = 0; c < NC; ++c) {
        float w = W1[c * NDH + tid];
#pragma unroll
        for (int nb = 0; nb < NB; ++nb)
#pragma unroll
            for (int v = 0; v < NV; ++v) h[nb][v] = fmaf(fs[nb][v][c], w, h[nb][v]);
    }
    {
        float w = W1[NC * NDH + tid];
#pragma unroll
        for (int nb = 0; nb < NB; ++nb)
#pragma unroll
            for (int v = 0; v < NV; ++v) h[nb][v] = fmaf(vis[nb][v], w, h[nb][v]);
    }

    float w2t = w2[tid];
    int lane = tid & 63, wave = tid >> 6;
#pragma unroll
    for (int nb = 0; nb < NB; ++nb) {
#pragma unroll
        for (int v = 0; v < NV; ++v) {
            float p = fmaxf(h[nb][v], 0.f) * w2t;
#pragma unroll
            for (int off = 32; off > 0; off >>= 1) p += __shfl_down(p, off);
            if (lane == 0) red[nb][v][wave] = p;
        }
    }
    __syncthreads();
    if (tid < NB * NV) {
        int nb = tid >> 2, v = tid & 3;
        sc[nb][v] = red[nb][v][0] + red[nb][v][1];
    }
    __syncthreads();
    if (tid < NB) {
        float s0 = sc[tid][0], s1 = sc[tid][1], s2 = sc[tid][2], s3 = sc[tid][3];
        float mx = fmaxf(fmaxf(s0, s1), fmaxf(s2, s3));
        float e0 = expf(s0 - mx), e1 = expf(s1 - mx);
        float e2 = expf(s2 - mx), e3 = expf(s3 - mx);
        float inv = 1.f / (e0 + e1 + e2 + e3);
        sc[tid][0] = e0 * inv; sc[tid][1] = e1 * inv;
        sc[tid][2] = e2 * inv; sc[tid][3] = e3 * inv;
    }
    __syncthreads();

#pragma unroll
    for (int nb = 0; nb < NB; ++nb) {
        int n = n0 + nb;
        float f = 0.f;
#pragma unroll
        for (int v = 0; v < NV; ++v) f += sc[nb][v] * fs[nb][v][tid];
        out[(size_t)n * OUTC + tid] = f;
        if (tid < 3) {
            float r = 0.f;
#pragma unroll
            for (int v = 0; v < NV; ++v) r += sc[nb][v] * rgbs[nb][v][tid];
            out[(size_t)n * OUTC + NC + tid] = r;
        }
    }
}

// ---------------------------------------------------------------------------
extern "C" void kernel_launch(void* const* d_in, const int* in_sizes, int n_in,
                              void* d_out, int out_size, void* d_ws, size_t ws_size,
                              hipStream_t stream) {
    const float* pts = (const float*)d_in[0];
    const float* extr = (const float*)d_in[1];
    const float* intr = (const float*)d_in[2];
    const float* zbuffer = (const float*)d_in[3];
    const float* feat = (const float*)d_in[4];
    const float* image = (const float*)d_in[5];
    const float* W1 = (const float*)d_in[6];
    const float* b1 = (const float*)d_in[7];
    const float* w2 = (const float*)d_in[8];
    float* out = (float*)d_out;

    float* uarr = (float*)d_ws;               // V*N
    float* varr = uarr + NV * NPT;            // V*N
    float* darr = varr + NV * NPT;            // V*N
    float* zarr = darr + NV * NPT;            // V*N
    int* mask = (int*)(zarr + NV * NPT);      // N

    int total = NV * NPT;
    k_project<<<(total + 255) / 256, 256, 0, stream>>>(pts, extr, intr, zbuffer,
                                                       uarr, varr, darr, zarr);
    k_mask<<<(NPT + 255) / 256, 256, 0, stream>>>(zarr, mask);
    k_knn<<<(NPT + 255) / 256, 256, 0, stream>>>(pts, mask, zarr);
    k_fused<<<NPT / NB, 128, 0, stream>>>(uarr, varr, darr, zarr, feat, image,
                                          W1, b1, w2, out);
}

// Round 4
// 736.320 us; speedup vs baseline: 2.2442x; 2.2442x over previous
//
#include <hip/hip_runtime.h>
#include <math.h>

#define NV 4
#define NPT 65536
#define NC 128
#define IMH 512
#define IMW 512
#define MPOOL 1024
#define NDH 128
#define KNN 5
#define NB 4
#define OUTC 131

typedef unsigned int uint32;
typedef unsigned short ushort16;

__device__ inline ushort16 f2bf(float f) {           // round-to-nearest-even
    uint32 u = __float_as_uint(f);
    u += 0x7fffu + ((u >> 16) & 1u);
    return (ushort16)(u >> 16);
}
__device__ inline float bflo(uint32 a) { return __uint_as_float(a << 16); }
__device__ inline float bfhi(uint32 a) { return __uint_as_float(a & 0xffff0000u); }
__device__ inline float bf1(ushort16 a) { return __uint_as_float(((uint32)a) << 16); }

// ---------------------------------------------------------------------------
// Kernel A: project points into each view + bilinear sample zbuffer
// ---------------------------------------------------------------------------
__global__ void k_project(const float* __restrict__ pts,
                          const float* __restrict__ extr,
                          const float* __restrict__ intr,
                          const float* __restrict__ zbuffer,
                          float* __restrict__ uarr, float* __restrict__ varr,
                          float* __restrict__ darr, float* __restrict__ zarr) {
    int idx = blockIdx.x * blockDim.x + threadIdx.x;
    if (idx >= NV * NPT) return;
    int v = idx >> 16;
    int n = idx & (NPT - 1);
    float p0 = pts[3 * n], p1 = pts[3 * n + 1], p2 = pts[3 * n + 2];
    const float* e = extr + v * 12;
    float c0 = e[0] * p0 + e[1] * p1 + e[2] * p2 + e[3];
    float c1 = e[4] * p0 + e[5] * p1 + e[6] * p2 + e[7];
    float c2 = e[8] * p0 + e[9] * p1 + e[10] * p2 + e[11];
    const float* kk = intr + v * 9;
    float x0 = kk[0] * c0 + kk[1] * c1 + kk[2] * c2;
    float x1 = kk[3] * c0 + kk[4] * c1 + kk[5] * c2;
    float x2 = kk[6] * c0 + kk[7] * c1 + kk[8] * c2;
    float uu = x0 / (x2 + 1e-9f);
    float vv = x1 / (x2 + 1e-9f);
    uarr[idx] = uu;
    varr[idx] = vv;
    darr[idx] = c2;

    const float* img = zbuffer + (size_t)v * IMH * IMW;
    float u0f = floorf(uu), v0f = floorf(vv);
    float du = uu - u0f, dv = vv - v0f;
    int iu0 = (int)u0f, iv0 = (int)v0f;
    float w00 = (1.f - du) * (1.f - dv);
    float w01 = du * (1.f - dv);
    float w10 = (1.f - du) * dv;
    float w11 = du * dv;
    int iu0c = min(max(iu0, 0), IMW - 1), iu1c = min(max(iu0 + 1, 0), IMW - 1);
    int iv0c = min(max(iv0, 0), IMH - 1), iv1c = min(max(iv0 + 1, 0), IMH - 1);
    float m00 = (iu0 >= 0 && iu0 < IMW && iv0 >= 0 && iv0 < IMH) ? w00 : 0.f;
    float m01 = (iu0 + 1 >= 0 && iu0 + 1 < IMW && iv0 >= 0 && iv0 < IMH) ? w01 : 0.f;
    float m10 = (iu0 >= 0 && iu0 < IMW && iv0 + 1 >= 0 && iv0 + 1 < IMH) ? w10 : 0.f;
    float m11 = (iu0 + 1 >= 0 && iu0 + 1 < IMW && iv0 + 1 >= 0 && iv0 + 1 < IMH) ? w11 : 0.f;
    float z = img[iv0c * IMW + iu0c] * m00 + img[iv0c * IMW + iu1c] * m01 +
              img[iv1c * IMW + iu0c] * m10 + img[iv1c * IMW + iu1c] * m11;
    zarr[idx] = z;
}

// ---------------------------------------------------------------------------
__global__ void k_mask(const float* __restrict__ zarr, int* __restrict__ mask) {
    int n = blockIdx.x * blockDim.x + threadIdx.x;
    if (n >= NPT) return;
    int m = 0;
#pragma unroll
    for (int v = 0; v < NV; ++v) m |= (zarr[v * NPT + n] == 0.f);
    mask[n] = m;
}

// ---------------------------------------------------------------------------
__global__ void k_knn(const float* __restrict__ pts, const int* __restrict__ mask,
                      float* __restrict__ zarr) {
    int n = blockIdx.x * blockDim.x + threadIdx.x;
    if (n >= NPT) return;
    if (!mask[n]) return;
    float px = pts[3 * n], py = pts[3 * n + 1], pz = pts[3 * n + 2];
    float bd[KNN];
    int bi[KNN];
#pragma unroll
    for (int k = 0; k < KNN; ++k) { bd[k] = INFINITY; bi[k] = 0; }
    for (int m = 0; m < MPOOL; ++m) {
        float dx = px - pts[3 * m];
        float dy = py - pts[3 * m + 1];
        float dz = pz - pts[3 * m + 2];
        float d2 = dx * dx + dy * dy + dz * dz;
        if (mask[m]) d2 = INFINITY;
        float d = d2;
        int id = m;
#pragma unroll
        for (int k = 0; k < KNN; ++k) {
            if (d < bd[k]) {
                float td = bd[k]; int ti = bi[k];
                bd[k] = d; bi[k] = id;
                d = td; id = ti;
            }
        }
    }
    float disp[KNN];
    float s = 0.f;
#pragma unroll
    for (int k = 0; k < KNN; ++k) {
        float dist = sqrtf(fmaxf(bd[k], 0.f));
        disp[k] = 1.f / (dist + 1e-8f);
        s += disp[k];
    }
    float inv = 1.f / (s + 1e-12f);
#pragma unroll
    for (int v = 0; v < NV; ++v) {
        float r = 0.f;
#pragma unroll
        for (int k = 0; k < KNN; ++k) r += zarr[v * NPT + bi[k]] * (disp[k] * inv);
        zarr[v * NPT + n] = r;
    }
}

// ---------------------------------------------------------------------------
// Transpose feat [V,C,H,W] f32 -> tfeat [V,H,W,C] bf16.
// Tile: 128 pixels (x-run) x 128 channels. Block 256.
// ---------------------------------------------------------------------------
__global__ __launch_bounds__(256)
void k_tfeat(const float* __restrict__ feat, ushort16* __restrict__ tfeat) {
    __shared__ ushort16 tile[128][130];   // [pix][ch], pad->row stride 130 (2-way max)
    int bid = blockIdx.x;
    int xt = bid & 3;                      // W/128 = 4
    int y = (bid >> 2) & 511;
    int v = bid >> 11;                     // 2048 blocks per view
    int x0 = xt * 128;
    int lane = threadIdx.x & 63, wave = threadIdx.x >> 6;
    const size_t HW = (size_t)IMH * IMW;
    const float* src = feat + (size_t)v * NC * HW + (size_t)y * IMW + x0;
#pragma unroll
    for (int i = 0; i < 32; ++i) {
        int c = i * 4 + wave;
        float2 val = *(const float2*)(src + (size_t)c * HW + lane * 2);
        tile[lane * 2][c] = f2bf(val.x);
        tile[lane * 2 + 1][c] = f2bf(val.y);
    }
    __syncthreads();
    uint32* dst = (uint32*)tfeat + ((size_t)v * HW + (size_t)y * IMW + x0) * 64;
#pragma unroll
    for (int i = 0; i < 32; ++i) {
        int pix = i * 4 + wave;
        uint32 val = *(const uint32*)&tile[pix][2 * lane];   // byte = pix*260 + 4*lane, aligned
        dst[(size_t)pix * 64 + lane] = val;
    }
}

// ---------------------------------------------------------------------------
// Transpose image [V,3,H,W] f32 -> trgb [V,H,W,4] bf16
// ---------------------------------------------------------------------------
__global__ __launch_bounds__(256)
void k_trgb(const float* __restrict__ image, ushort16* __restrict__ trgb) {
    int bid = blockIdx.x;
    int xt = bid & 1, y = (bid >> 1) & 511, v = bid >> 10;
    int x = xt * 256 + threadIdx.x;
    const size_t HW = (size_t)IMH * IMW;
    size_t p = (size_t)y * IMW + x;
    const float* src = image + (size_t)v * 3 * HW;
    ushort4 o;
    o.x = f2bf(src[p]);
    o.y = f2bf(src[HW + p]);
    o.z = f2bf(src[2 * HW + p]);
    o.w = 0;
    *(ushort4*)(trgb + ((size_t)v * HW + p) * 4) = o;
}

// ---------------------------------------------------------------------------
// Fused sampling + MLP + softmax + blend, reading transposed bf16 maps.
// Block 128 threads handles NB=4 points x 4 views (q = nb*4+v in [0,16)).
// ---------------------------------------------------------------------------
__global__ __launch_bounds__(128)
void k_fused_t(const float* __restrict__ uarr, const float* __restrict__ varr,
               const float* __restrict__ darr, const float* __restrict__ zarr,
               const ushort16* __restrict__ tfeat, const ushort16* __restrict__ trgb,
               const float* __restrict__ W1, const float* __restrict__ b1,
               const float* __restrict__ w2, float* __restrict__ out) {
    const int tid = threadIdx.x;
    const int n0 = blockIdx.x * NB;
    const size_t HW = (size_t)IMH * IMW;
    __shared__ float fs[16][NC];
    __shared__ float rgbs[16][3];
    __shared__ int po[16][4];
    __shared__ float pm[16][4];
    __shared__ float viss[16];
    __shared__ float sc[16];
    __shared__ float red[16][2];

    if (tid < 16) {
        int nb = tid >> 2, v = tid & 3;
        int vn = v * NPT + n0 + nb;
        float uu = uarr[vn], vv = varr[vn];
        float u0f = floorf(uu), v0f = floorf(vv);
        float du = uu - u0f, dv = vv - v0f;
        int iu0 = (int)u0f, iv0 = (int)v0f;
        float w00 = (1.f - du) * (1.f - dv);
        float w01 = du * (1.f - dv);
        float w10 = (1.f - du) * dv;
        float w11 = du * dv;
        int iu0c = min(max(iu0, 0), IMW - 1), iu1c = min(max(iu0 + 1, 0), IMW - 1);
        int iv0c = min(max(iv0, 0), IMH - 1), iv1c = min(max(iv0 + 1, 0), IMH - 1);
        float m00 = (iu0 >= 0 && iu0 < IMW && iv0 >= 0 && iv0 < IMH) ? w00 : 0.f;
        float m01 = (iu0 + 1 < IMW && iu0 + 1 >= 0 && iv0 >= 0 && iv0 < IMH) ? w01 : 0.f;
        float m10 = (iu0 >= 0 && iu0 < IMW && iv0 + 1 < IMH && iv0 + 1 >= 0) ? w10 : 0.f;
        float m11 = (iu0 + 1 < IMW && iu0 + 1 >= 0 && iv0 + 1 < IMH && iv0 + 1 >= 0) ? w11 : 0.f;
        int o00 = iv0c * IMW + iu0c, o01 = iv0c * IMW + iu1c;
        int o10 = iv1c * IMW + iu0c, o11 = iv1c * IMW + iu1c;
        po[tid][0] = o00; po[tid][1] = o01; po[tid][2] = o10; po[tid][3] = o11;
        pm[tid][0] = m00; pm[tid][1] = m01; pm[tid][2] = m10; pm[tid][3] = m11;
        float z = zarr[vn], dd = darr[vn];
        viss[tid] = 1.f - fabsf(z - dd) / (z + 1e-9f);
        // rgb sample (bf16, [pix][4])
        const ushort16* rb = trgb + (size_t)v * HW * 4;
        float ar = 0.f, ag = 0.f, ab = 0.f;
        int oo[4] = {o00, o01, o10, o11};
        float mm[4] = {m00, m01, m10, m11};
#pragma unroll
        for (int k = 0; k < 4; ++k) {
            const ushort16* c = rb + (size_t)oo[k] * 4;
            ar += bf1(c[0]) * mm[k];
            ag += bf1(c[1]) * mm[k];
            ab += bf1(c[2]) * mm[k];
        }
        rgbs[tid][0] = ar; rgbs[tid][1] = ag; rgbs[tid][2] = ab;
    }
    __syncthreads();

    // sampling: 8 iterations, each half-wave (sub) takes one q; lane=channel pair
    const uint32* T = (const uint32*)tfeat;    // 64 uints per pixel
    int sub = tid >> 6, c2 = tid & 63;
#pragma unroll
    for (int i = 0; i < 8; ++i) {
        int q = i * 2 + sub;
        int v = q & 3;
        const uint32* B = T + (size_t)v * HW * 64;
        int o0 = po[q][0], o1 = po[q][1], o2 = po[q][2], o3 = po[q][3];
        float m0 = pm[q][0], m1 = pm[q][1], m2 = pm[q][2], m3 = pm[q][3];
        uint32 a0 = B[(size_t)o0 * 64 + c2];
        uint32 a1 = B[(size_t)o1 * 64 + c2];
        uint32 a2 = B[(size_t)o2 * 64 + c2];
        uint32 a3 = B[(size_t)o3 * 64 + c2];
        float lo = bflo(a0) * m0 + bflo(a1) * m1 + bflo(a2) * m2 + bflo(a3) * m3;
        float hi = bfhi(a0) * m0 + bfhi(a1) * m1 + bfhi(a2) * m2 + bfhi(a3) * m3;
        *(float2*)&fs[q][2 * c2] = make_float2(lo, hi);
    }
    __syncthreads();

    // MLP: thread = hidden dim d; c outer so one W1 element feeds 16 FMAs
    float h[16];
    float bv = b1[tid];
#pragma unroll
    for (int q = 0; q < 16; ++q) h[q] = bv;
    for (int c = 0; c < NC; ++c) {
        float w = W1[c * NDH + tid];
#pragma unroll
        for (int q = 0; q < 16; ++q) h[q] = fmaf(fs[q][c], w, h[q]);
    }
    {
        float w = W1[NC * NDH + tid];
#pragma unroll
        for (int q = 0; q < 16; ++q) h[q] = fmaf(viss[q], w, h[q]);
    }

    float w2t = w2[tid];
    int lane = tid & 63, wave = tid >> 6;
#pragma unroll
    for (int q = 0; q < 16; ++q) {
        float p = fmaxf(h[q], 0.f) * w2t;
#pragma unroll
        for (int off = 32; off > 0; off >>= 1) p += __shfl_down(p, off);
        if (lane == 0) red[q][wave] = p;
    }
    __syncthreads();
    if (tid < 16) sc[tid] = red[tid][0] + red[tid][1];
    __syncthreads();
    if (tid < NB) {
        float s0 = sc[tid * 4 + 0], s1 = sc[tid * 4 + 1];
        float s2 = sc[tid * 4 + 2], s3 = sc[tid * 4 + 3];
        float mx = fmaxf(fmaxf(s0, s1), fmaxf(s2, s3));
        float e0 = expf(s0 - mx), e1 = expf(s1 - mx);
        float e2 = expf(s2 - mx), e3 = expf(s3 - mx);
        float inv = 1.f / (e0 + e1 + e2 + e3);
        sc[tid * 4 + 0] = e0 * inv; sc[tid * 4 + 1] = e1 * inv;
        sc[tid * 4 + 2] = e2 * inv; sc[tid * 4 + 3] = e3 * inv;
    }
    __syncthreads();

#pragma unroll
    for (int nb = 0; nb < NB; ++nb) {
        int n = n0 + nb;
        float f = 0.f;
#pragma unroll
        for (int v = 0; v < NV; ++v) f += sc[nb * 4 + v] * fs[nb * 4 + v][tid];
        out[(size_t)n * OUTC + tid] = f;
        if (tid < 3) {
            float r = 0.f;
#pragma unroll
            for (int v = 0; v < NV; ++v) r += sc[nb * 4 + v] * rgbs[nb * 4 + v][tid];
            out[(size_t)n * OUTC + NC + tid] = r;
        }
    }
}

// ---------------------------------------------------------------------------
// Fallback fused kernel (direct [V,C,H,W] reads) — used only if ws too small.
// ---------------------------------------------------------------------------
__global__ __launch_bounds__(128)
void k_fused_d(const float* __restrict__ uarr, const float* __restrict__ varr,
               const float* __restrict__ darr, const float* __restrict__ zarr,
               const float* __restrict__ feat, const float* __restrict__ image,
               const float* __restrict__ W1, const float* __restrict__ b1,
               const float* __restrict__ w2, float* __restrict__ out) {
    const int tid = threadIdx.x;
    const int n0 = blockIdx.x * NB;
    __shared__ float fs[NB][NV][NC];
    __shared__ float rgbs[NB][NV][3];
    __shared__ float sc[NB][NV];
    __shared__ float red[NB][NV][2];
    float vis[NB][NV];

#pragma unroll
    for (int nb = 0; nb < NB; ++nb) {
        int n = n0 + nb;
#pragma unroll
        for (int v = 0; v < NV; ++v) {
            int vn = v * NPT + n;
            float uu = uarr[vn], vv = varr[vn];
            float u0f = floorf(uu), v0f = floorf(vv);
            float du = uu - u0f, dv = vv - v0f;
            int iu0 = (int)u0f, iv0 = (int)v0f;
            float w00 = (1.f - du) * (1.f - dv);
            float w01 = du * (1.f - dv);
            float w10 = (1.f - du) * dv;
            float w11 = du * dv;
            int iu0c = min(max(iu0, 0), IMW - 1), iu1c = min(max(iu0 + 1, 0), IMW - 1);
            int iv0c = min(max(iv0, 0), IMH - 1), iv1c = min(max(iv0 + 1, 0), IMH - 1);
            float m00 = (iu0 >= 0 && iu0 < IMW && iv0 >= 0 && iv0 < IMH) ? w00 : 0.f;
            float m01 = (iu0 + 1 < IMW && iu0 + 1 >= 0 && iv0 >= 0 && iv0 < IMH) ? w01 : 0.f;
            float m10 = (iu0 >= 0 && iu0 < IMW && iv0 + 1 < IMH && iv0 + 1 >= 0) ? w10 : 0.f;
            float m11 = (iu0 + 1 < IMW && iu0 + 1 >= 0 && iv0 + 1 < IMH && iv0 + 1 >= 0) ? w11 : 0.f;
            int o00 = iv0c * IMW + iu0c, o01 = iv0c * IMW + iu1c;
            int o10 = iv1c * IMW + iu0c, o11 = iv1c * IMW + iu1c;
            const float* base = feat + ((size_t)(v * NC + tid)) * IMH * IMW;
            fs[nb][v][tid] = base[o00] * m00 + base[o01] * m01 +
                             base[o10] * m10 + base[o11] * m11;
            if (tid < 3) {
                const float* ib = image + ((size_t)(v * 3 + tid)) * IMH * IMW;
                rgbs[nb][v][tid] = ib[o00] * m00 + ib[o01] * m01 +
                                   ib[o10] * m10 + ib[o11] * m11;
            }
            float z = zarr[vn], dd = darr[vn];
            vis[nb][v] = 1.f - fabsf(z - dd) / (z + 1e-9f);
        }
    }
    __syncthreads();

    float h[NB][NV];
    float bv = b1[tid];
#pragma unroll
    for (int nb = 0; nb < NB; ++nb)
#pragma unroll
        for (int v = 0; v < NV; ++v) h[nb][v] = bv;
    for (int c = 0; c < NC; ++c) {
        float w = W1[c * NDH + tid];
#pragma unroll
        for (int nb = 0; nb < NB; ++nb)
#pragma unroll
            for (int v = 0; v < NV; ++v) h[nb][v] = fmaf(fs[nb][v][c], w, h[nb][v]);
    }
    {
        float w = W1[NC * NDH + tid];
#pragma unroll
        for (int nb = 0; nb < NB; ++nb)
#pragma unroll
            for (int v = 0; v < NV; ++v) h[nb][v] = fmaf(vis[nb][v], w, h[nb][v]);
    }
    float w2t = w2[tid];
    int lane = tid & 63, wave = tid >> 6;
#pragma unroll
    for (int nb = 0; nb < NB; ++nb) {
#pragma unroll
        for (int v = 0; v < NV; ++v) {
            float p = fmaxf(h[nb][v], 0.f) * w2t;
#pragma unroll
            for (int off = 32; off > 0; off >>= 1) p += __shfl_down(p, off);
            if (lane == 0) red[nb][v][wave] = p;
        }
    }
    __syncthreads();
    if (tid < NB * NV) {
        int nb = tid >> 2, v = tid & 3;
        sc[nb][v] = red[nb][v][0] + red[nb][v][1];
    }
    __syncthreads();
    if (tid < NB) {
        float s0 = sc[tid][0], s1 = sc[tid][1], s2 = sc[tid][2], s3 = sc[tid][3];
        float mx = fmaxf(fmaxf(s0, s1), fmaxf(s2, s3));
        float e0 = expf(s0 - mx), e1 = expf(s1 - mx);
        float e2 = expf(s2 - mx), e3 = expf(s3 - mx);
        float inv = 1.f / (e0 + e1 + e2 + e3);
        sc[tid][0] = e0 * inv; sc[tid][1] = e1 * inv;
        sc[tid][2] = e2 * inv; sc[tid][3] = e3 * inv;
    }
    __syncthreads();
#pragma unroll
    for (int nb = 0; nb < NB; ++nb) {
        int n = n0 + nb;
        float f = 0.f;
#pragma unroll
        for (int v = 0; v < NV; ++v) f += sc[nb][v] * fs[nb][v][tid];
        out[(size_t)n * OUTC + tid] = f;
        if (tid < 3) {
            float r = 0.f;
#pragma unroll
            for (int v = 0; v < NV; ++v) r += sc[nb][v] * rgbs[nb][v][tid];
            out[(size_t)n * OUTC + NC + tid] = r;
        }
    }
}

// ---------------------------------------------------------------------------
extern "C" void kernel_launch(void* const* d_in, const int* in_sizes, int n_in,
                              void* d_out, int out_size, void* d_ws, size_t ws_size,
                              hipStream_t stream) {
    const float* pts = (const float*)d_in[0];
    const float* extr = (const float*)d_in[1];
    const float* intr = (const float*)d_in[2];
    const float* zbuffer = (const float*)d_in[3];
    const float* feat = (const float*)d_in[4];
    const float* image = (const float*)d_in[5];
    const float* W1 = (const float*)d_in[6];
    const float* b1 = (const float*)d_in[7];
    const float* w2 = (const float*)d_in[8];
    float* out = (float*)d_out;

    const size_t VN = (size_t)NV * NPT;
    float* uarr = (float*)d_ws;
    float* varr = uarr + VN;
    float* darr = varr + VN;
    float* zarr = darr + VN;
    int* mask = (int*)(zarr + VN);
    char* after = (char*)(mask + NPT);                         // 4,456,448 B
    ushort16* trgb = (ushort16*)after;                         // V*H*W*4 bf16 = 8 MB
    ushort16* tfeat = (ushort16*)(after + (size_t)NV * IMH * IMW * 4 * 2);  // 256 MB
    size_t need = (size_t)((char*)tfeat - (char*)d_ws) + (size_t)NV * IMH * IMW * NC * 2;

    int total = NV * NPT;
    k_project<<<(total + 255) / 256, 256, 0, stream>>>(pts, extr, intr, zbuffer,
                                                       uarr, varr, darr, zarr);
    k_mask<<<(NPT + 255) / 256, 256, 0, stream>>>(zarr, mask);
    k_knn<<<(NPT + 255) / 256, 256, 0, stream>>>(pts, mask, zarr);

    if (ws_size >= need) {
        k_tfeat<<<NV * 512 * 4, 256, 0, stream>>>(feat, tfeat);
        k_trgb<<<NV * 512 * 2, 256, 0, stream>>>(image, trgb);
        k_fused_t<<<NPT / NB, 128, 0, stream>>>(uarr, varr, darr, zarr, tfeat, trgb,
                                                W1, b1, w2, out);
    } else {
        k_fused_d<<<NPT / NB, 128, 0, stream>>>(uarr, varr, darr, zarr, feat, image,
                                                W1, b1, w2, out);
    }
}

// Round 5
// 604.069 us; speedup vs baseline: 2.7355x; 1.2189x over previous
//
#include <hip/hip_runtime.h>
#include <math.h>

#define NV 4
#define NPT 65536
#define NC 128
#define IMH 512
#define IMW 512
#define MPOOL 1024
#define NDH 128
#define KNN 5
#define NB 4
#define OUTC 131

typedef unsigned int uint32;
typedef unsigned short ushort16;

__device__ inline ushort16 f2bf(float f) {           // round-to-nearest-even
    uint32 u = __float_as_uint(f);
    u += 0x7fffu + ((u >> 16) & 1u);
    return (ushort16)(u >> 16);
}
__device__ inline float bflo(uint32 a) { return __uint_as_float(a << 16); }
__device__ inline float bfhi(uint32 a) { return __uint_as_float(a & 0xffff0000u); }
__device__ inline float bf1(ushort16 a) { return __uint_as_float(((uint32)a) << 16); }

// ---------------------------------------------------------------------------
__global__ void k_zero(int* __restrict__ counter) {
    if (threadIdx.x == 0 && blockIdx.x == 0) *counter = 0;
}

// ---------------------------------------------------------------------------
// Kernel A: project points into each view + bilinear sample zbuffer
// ---------------------------------------------------------------------------
__global__ void k_project(const float* __restrict__ pts,
                          const float* __restrict__ extr,
                          const float* __restrict__ intr,
                          const float* __restrict__ zbuffer,
                          float* __restrict__ uarr, float* __restrict__ varr,
                          float* __restrict__ darr, float* __restrict__ zarr) {
    int idx = blockIdx.x * blockDim.x + threadIdx.x;
    if (idx >= NV * NPT) return;
    int v = idx >> 16;
    int n = idx & (NPT - 1);
    float p0 = pts[3 * n], p1 = pts[3 * n + 1], p2 = pts[3 * n + 2];
    const float* e = extr + v * 12;
    float c0 = e[0] * p0 + e[1] * p1 + e[2] * p2 + e[3];
    float c1 = e[4] * p0 + e[5] * p1 + e[6] * p2 + e[7];
    float c2 = e[8] * p0 + e[9] * p1 + e[10] * p2 + e[11];
    const float* kk = intr + v * 9;
    float x0 = kk[0] * c0 + kk[1] * c1 + kk[2] * c2;
    float x1 = kk[3] * c0 + kk[4] * c1 + kk[5] * c2;
    float x2 = kk[6] * c0 + kk[7] * c1 + kk[8] * c2;
    float uu = x0 / (x2 + 1e-9f);
    float vv = x1 / (x2 + 1e-9f);
    uarr[idx] = uu;
    varr[idx] = vv;
    darr[idx] = c2;

    const float* img = zbuffer + (size_t)v * IMH * IMW;
    float u0f = floorf(uu), v0f = floorf(vv);
    float du = uu - u0f, dv = vv - v0f;
    int iu0 = (int)u0f, iv0 = (int)v0f;
    float w00 = (1.f - du) * (1.f - dv);
    float w01 = du * (1.f - dv);
    float w10 = (1.f - du) * dv;
    float w11 = du * dv;
    int iu0c = min(max(iu0, 0), IMW - 1), iu1c = min(max(iu0 + 1, 0), IMW - 1);
    int iv0c = min(max(iv0, 0), IMH - 1), iv1c = min(max(iv0 + 1, 0), IMH - 1);
    float m00 = (iu0 >= 0 && iu0 < IMW && iv0 >= 0 && iv0 < IMH) ? w00 : 0.f;
    float m01 = (iu0 + 1 >= 0 && iu0 + 1 < IMW && iv0 >= 0 && iv0 < IMH) ? w01 : 0.f;
    float m10 = (iu0 >= 0 && iu0 < IMW && iv0 + 1 >= 0 && iv0 + 1 < IMH) ? w10 : 0.f;
    float m11 = (iu0 + 1 >= 0 && iu0 + 1 < IMW && iv0 + 1 >= 0 && iv0 + 1 < IMH) ? w11 : 0.f;
    float z = img[iv0c * IMW + iu0c] * m00 + img[iv0c * IMW + iu1c] * m01 +
              img[iv1c * IMW + iu0c] * m10 + img[iv1c * IMW + iu1c] * m11;
    zarr[idx] = z;
}

// ---------------------------------------------------------------------------
// Kernel B: mask + stream-compaction of masked point indices.
// List order is nondeterministic (atomics) but per-point KNN results don't
// depend on list order, so the final output is deterministic.
// ---------------------------------------------------------------------------
__global__ void k_mask(const float* __restrict__ zarr, int* __restrict__ mask,
                       int* __restrict__ list, int* __restrict__ counter) {
    int n = blockIdx.x * blockDim.x + threadIdx.x;
    if (n >= NPT) return;
    int m = 0;
#pragma unroll
    for (int v = 0; v < NV; ++v) m |= (zarr[v * NPT + n] == 0.f);
    mask[n] = m;
    if (m) {
        int pos = atomicAdd(counter, 1);   // compiler coalesces per-wave
        list[pos] = n;
    }
}

// ---------------------------------------------------------------------------
// Kernel C: dense KNN over the compacted masked points only.
// Candidates staged in LDS (bad candidates get x=INF -> d2=INF -> never
// inserted, matching jax top_k-of-inf semantics where wknn weight = 0).
// ---------------------------------------------------------------------------
__global__ __launch_bounds__(256)
void k_knn_c(const float* __restrict__ pts, const int* __restrict__ mask,
             const int* __restrict__ list, const int* __restrict__ counter,
             float* __restrict__ zarr) {
    __shared__ float cx[MPOOL], cy[MPOOL], cz[MPOOL];
    int count = *counter;
    if ((int)blockIdx.x * 256 >= count) return;
    for (int m = threadIdx.x; m < MPOOL; m += 256) {
        int bad = mask[m];
        cx[m] = bad ? INFINITY : pts[3 * m];
        cy[m] = pts[3 * m + 1];
        cz[m] = pts[3 * m + 2];
    }
    __syncthreads();
    int i = blockIdx.x * 256 + threadIdx.x;
    if (i >= count) return;
    int n = list[i];
    float px = pts[3 * n], py = pts[3 * n + 1], pz = pts[3 * n + 2];
    float bd[KNN];
    int bi[KNN];
#pragma unroll
    for (int k = 0; k < KNN; ++k) { bd[k] = INFINITY; bi[k] = 0; }
    for (int m = 0; m < MPOOL; ++m) {
        float dx = px - cx[m];
        float dy = py - cy[m];
        float dz = pz - cz[m];
        float d = dx * dx + dy * dy + dz * dz;   // INF for bad candidates
        int id = m;
#pragma unroll
        for (int k = 0; k < KNN; ++k) {
            // strict < : ties keep the earlier (lower) index, matching jax top_k
            if (d < bd[k]) {
                float td = bd[k]; int ti = bi[k];
                bd[k] = d; bi[k] = id;
                d = td; id = ti;
            }
        }
    }
    float disp[KNN];
    float s = 0.f;
#pragma unroll
    for (int k = 0; k < KNN; ++k) {
        float dist = sqrtf(fmaxf(bd[k], 0.f));   // sqrt(inf)=inf -> disp 0
        disp[k] = 1.f / (dist + 1e-8f);
        s += disp[k];
    }
    float inv = 1.f / (s + 1e-12f);
#pragma unroll
    for (int v = 0; v < NV; ++v) {
        float r = 0.f;
#pragma unroll
        for (int k = 0; k < KNN; ++k) r += zarr[v * NPT + bi[k]] * (disp[k] * inv);
        zarr[v * NPT + n] = r;
    }
}

// ---------------------------------------------------------------------------
// Transpose feat [V,C,H,W] f32 -> tfeat [V,H,W,C] bf16.
// Tile: 128 pixels (x-run) x 128 channels. Block 256.
// ---------------------------------------------------------------------------
__global__ __launch_bounds__(256)
void k_tfeat(const float* __restrict__ feat, ushort16* __restrict__ tfeat) {
    __shared__ ushort16 tile[128][130];   // [pix][ch], pad->row stride 130 (2-way max)
    int bid = blockIdx.x;
    int xt = bid & 3;                      // W/128 = 4
    int y = (bid >> 2) & 511;
    int v = bid >> 11;                     // 2048 blocks per view
    int x0 = xt * 128;
    int lane = threadIdx.x & 63, wave = threadIdx.x >> 6;
    const size_t HW = (size_t)IMH * IMW;
    const float* src = feat + (size_t)v * NC * HW + (size_t)y * IMW + x0;
#pragma unroll
    for (int i = 0; i < 32; ++i) {
        int c = i * 4 + wave;
        float2 val = *(const float2*)(src + (size_t)c * HW + lane * 2);
        tile[lane * 2][c] = f2bf(val.x);
        tile[lane * 2 + 1][c] = f2bf(val.y);
    }
    __syncthreads();
    uint32* dst = (uint32*)tfeat + ((size_t)v * HW + (size_t)y * IMW + x0) * 64;
#pragma unroll
    for (int i = 0; i < 32; ++i) {
        int pix = i * 4 + wave;
        uint32 val = *(const uint32*)&tile[pix][2 * lane];   // byte = pix*260 + 4*lane, aligned
        dst[(size_t)pix * 64 + lane] = val;
    }
}

// ---------------------------------------------------------------------------
// Transpose image [V,3,H,W] f32 -> trgb [V,H,W,4] bf16
// ---------------------------------------------------------------------------
__global__ __launch_bounds__(256)
void k_trgb(const float* __restrict__ image, ushort16* __restrict__ trgb) {
    int bid = blockIdx.x;
    int xt = bid & 1, y = (bid >> 1) & 511, v = bid >> 10;
    int x = xt * 256 + threadIdx.x;
    const size_t HW = (size_t)IMH * IMW;
    size_t p = (size_t)y * IMW + x;
    const float* src = image + (size_t)v * 3 * HW;
    ushort4 o;
    o.x = f2bf(src[p]);
    o.y = f2bf(src[HW + p]);
    o.z = f2bf(src[2 * HW + p]);
    o.w = 0;
    *(ushort4*)(trgb + ((size_t)v * HW + p) * 4) = o;
}

// ---------------------------------------------------------------------------
// Fused sampling + MLP + softmax + blend, reading transposed bf16 maps.
// Block 128 threads handles NB=4 points x 4 views (q = nb*4+v in [0,16)).
// ---------------------------------------------------------------------------
__global__ __launch_bounds__(128)
void k_fused_t(const float* __restrict__ uarr, const float* __restrict__ varr,
               const float* __restrict__ darr, const float* __restrict__ zarr,
               const ushort16* __restrict__ tfeat, const ushort16* __restrict__ trgb,
               const float* __restrict__ W1, const float* __restrict__ b1,
               const float* __restrict__ w2, float* __restrict__ out) {
    const int tid = threadIdx.x;
    const int n0 = blockIdx.x * NB;
    const size_t HW = (size_t)IMH * IMW;
    __shared__ float fs[16][NC];
    __shared__ float rgbs[16][3];
    __shared__ int po[16][4];
    __shared__ float pm[16][4];
    __shared__ float viss[16];
    __shared__ float sc[16];
    __shared__ float red[16][2];

    if (tid < 16) {
        int nb = tid >> 2, v = tid & 3;
        int vn = v * NPT + n0 + nb;
        float uu = uarr[vn], vv = varr[vn];
        float u0f = floorf(uu), v0f = floorf(vv);
        float du = uu - u0f, dv = vv - v0f;
        int iu0 = (int)u0f, iv0 = (int)v0f;
        float w00 = (1.f - du) * (1.f - dv);
        float w01 = du * (1.f - dv);
        float w10 = (1.f - du) * dv;
        float w11 = du * dv;
        int iu0c = min(max(iu0, 0), IMW - 1), iu1c = min(max(iu0 + 1, 0), IMW - 1);
        int iv0c = min(max(iv0, 0), IMH - 1), iv1c = min(max(iv0 + 1, 0), IMH - 1);
        float m00 = (iu0 >= 0 && iu0 < IMW && iv0 >= 0 && iv0 < IMH) ? w00 : 0.f;
        float m01 = (iu0 + 1 < IMW && iu0 + 1 >= 0 && iv0 >= 0 && iv0 < IMH) ? w01 : 0.f;
        float m10 = (iu0 >= 0 && iu0 < IMW && iv0 + 1 < IMH && iv0 + 1 >= 0) ? w10 : 0.f;
        float m11 = (iu0 + 1 < IMW && iu0 + 1 >= 0 && iv0 + 1 < IMH && iv0 + 1 >= 0) ? w11 : 0.f;
        int o00 = iv0c * IMW + iu0c, o01 = iv0c * IMW + iu1c;
        int o10 = iv1c * IMW + iu0c, o11 = iv1c * IMW + iu1c;
        po[tid][0] = o00; po[tid][1] = o01; po[tid][2] = o10; po[tid][3] = o11;
        pm[tid][0] = m00; pm[tid][1] = m01; pm[tid][2] = m10; pm[tid][3] = m11;
        float z = zarr[vn], dd = darr[vn];
        viss[tid] = 1.f - fabsf(z - dd) / (z + 1e-9f);
        // rgb sample (bf16, [pix][4])
        const ushort16* rb = trgb + (size_t)v * HW * 4;
        float ar = 0.f, ag = 0.f, ab = 0.f;
        int oo[4] = {o00, o01, o10, o11};
        float mm[4] = {m00, m01, m10, m11};
#pragma unroll
        for (int k = 0; k < 4; ++k) {
            const ushort16* c = rb + (size_t)oo[k] * 4;
            ar += bf1(c[0]) * mm[k];
            ag += bf1(c[1]) * mm[k];
            ab += bf1(c[2]) * mm[k];
        }
        rgbs[tid][0] = ar; rgbs[tid][1] = ag; rgbs[tid][2] = ab;
    }
    __syncthreads();

    // sampling: 8 iterations, each half-wave (sub) takes one q; lane=channel pair
    const uint32* T = (const uint32*)tfeat;    // 64 uints per pixel
    int sub = tid >> 6, c2 = tid & 63;
#pragma unroll
    for (int i = 0; i < 8; ++i) {
        int q = i * 2 + sub;
        int v = q & 3;
        const uint32* B = T + (size_t)v * HW * 64;
        int o0 = po[q][0], o1 = po[q][1], o2 = po[q][2], o3 = po[q][3];
        float m0 = pm[q][0], m1 = pm[q][1], m2 = pm[q][2], m3 = pm[q][3];
        uint32 a0 = B[(size_t)o0 * 64 + c2];
        uint32 a1 = B[(size_t)o1 * 64 + c2];
        uint32 a2 = B[(size_t)o2 * 64 + c2];
        uint32 a3 = B[(size_t)o3 * 64 + c2];
        float lo = bflo(a0) * m0 + bflo(a1) * m1 + bflo(a2) * m2 + bflo(a3) * m3;
        float hi = bfhi(a0) * m0 + bfhi(a1) * m1 + bfhi(a2) * m2 + bfhi(a3) * m3;
        *(float2*)&fs[q][2 * c2] = make_float2(lo, hi);
    }
    __syncthreads();

    // MLP: thread = hidden dim d; c outer so one W1 element feeds 16 FMAs
    float h[16];
    float bv = b1[tid];
#pragma unroll
    for (int q = 0; q < 16; ++q) h[q] = bv;
    for (int c = 0; c < NC; ++c) {
        float w = W1[c * NDH + tid];
#pragma unroll
        for (int q = 0; q < 16; ++q) h[q] = fmaf(fs[q][c], w, h[q]);
    }
    {
        float w = W1[NC * NDH + tid];
#pragma unroll
        for (int q = 0; q < 16; ++q) h[q] = fmaf(viss[q], w, h[q]);
    }

    float w2t = w2[tid];
    int lane = tid & 63, wave = tid >> 6;
#pragma unroll
    for (int q = 0; q < 16; ++q) {
        float p = fmaxf(h[q], 0.f) * w2t;
#pragma unroll
        for (int off = 32; off > 0; off >>= 1) p += __shfl_down(p, off);
        if (lane == 0) red[q][wave] = p;
    }
    __syncthreads();
    if (tid < 16) sc[tid] = red[tid][0] + red[tid][1];
    __syncthreads();
    if (tid < NB) {
        float s0 = sc[tid * 4 + 0], s1 = sc[tid * 4 + 1];
        float s2 = sc[tid * 4 + 2], s3 = sc[tid * 4 + 3];
        float mx = fmaxf(fmaxf(s0, s1), fmaxf(s2, s3));
        float e0 = expf(s0 - mx), e1 = expf(s1 - mx);
        float e2 = expf(s2 - mx), e3 = expf(s3 - mx);
        float inv = 1.f / (e0 + e1 + e2 + e3);
        sc[tid * 4 + 0] = e0 * inv; sc[tid * 4 + 1] = e1 * inv;
        sc[tid * 4 + 2] = e2 * inv; sc[tid * 4 + 3] = e3 * inv;
    }
    __syncthreads();

#pragma unroll
    for (int nb = 0; nb < NB; ++nb) {
        int n = n0 + nb;
        float f = 0.f;
#pragma unroll
        for (int v = 0; v < NV; ++v) f += sc[nb * 4 + v] * fs[nb * 4 + v][tid];
        out[(size_t)n * OUTC + tid] = f;
        if (tid < 3) {
            float r = 0.f;
#pragma unroll
            for (int v = 0; v < NV; ++v) r += sc[nb * 4 + v] * rgbs[nb * 4 + v][tid];
            out[(size_t)n * OUTC + NC + tid] = r;
        }
    }
}

// ---------------------------------------------------------------------------
// Fallback fused kernel (direct [V,C,H,W] reads) — used only if ws too small.
// ---------------------------------------------------------------------------
__global__ __launch_bounds__(128)
void k_fused_d(const float* __restrict__ uarr, const float* __restrict__ varr,
               const float* __restrict__ darr, const float* __restrict__ zarr,
               const float* __restrict__ feat, const float* __restrict__ image,
               const float* __restrict__ W1, const float* __restrict__ b1,
               const float* __restrict__ w2, float* __restrict__ out) {
    const int tid = threadIdx.x;
    const int n0 = blockIdx.x * NB;
    __shared__ float fs[NB][NV][NC];
    __shared__ float rgbs[NB][NV][3];
    __shared__ float sc[NB][NV];
    __shared__ float red[NB][NV][2];
    float vis[NB][NV];

#pragma unroll
    for (int nb = 0; nb < NB; ++nb) {
        int n = n0 + nb;
#pragma unroll
        for (int v = 0; v < NV; ++v) {
            int vn = v * NPT + n;
            float uu = uarr[vn], vv = varr[vn];
            float u0f = floorf(uu), v0f = floorf(vv);
            float du = uu - u0f, dv = vv - v0f;
            int iu0 = (int)u0f, iv0 = (int)v0f;
            float w00 = (1.f - du) * (1.f - dv);
            float w01 = du * (1.f - dv);
            float w10 = (1.f - du) * dv;
            float w11 = du * dv;
            int iu0c = min(max(iu0, 0), IMW - 1), iu1c = min(max(iu0 + 1, 0), IMW - 1);
            int iv0c = min(max(iv0, 0), IMH - 1), iv1c = min(max(iv0 + 1, 0), IMH - 1);
            float m00 = (iu0 >= 0 && iu0 < IMW && iv0 >= 0 && iv0 < IMH) ? w00 : 0.f;
            float m01 = (iu0 + 1 < IMW && iu0 + 1 >= 0 && iv0 >= 0 && iv0 < IMH) ? w01 : 0.f;
            float m10 = (iu0 >= 0 && iu0 < IMW && iv0 + 1 < IMH && iv0 + 1 >= 0) ? w10 : 0.f;
            float m11 = (iu0 + 1 < IMW && iu0 + 1 >= 0 && iv0 + 1 < IMH && iv0 + 1 >= 0) ? w11 : 0.f;
            int o00 = iv0c * IMW + iu0c, o01 = iv0c * IMW + iu1c;
            int o10 = iv1c * IMW + iu0c, o11 = iv1c * IMW + iu1c;
            const float* base = feat + ((size_t)(v * NC + tid)) * IMH * IMW;
            fs[nb][v][tid] = base[o00] * m00 + base[o01] * m01 +
                             base[o10] * m10 + base[o11] * m11;
            if (tid < 3) {
                const float* ib = image + ((size_t)(v * 3 + tid)) * IMH * IMW;
                rgbs[nb][v][tid] = ib[o00] * m00 + ib[o01] * m01 +
                                   ib[o10] * m10 + ib[o11] * m11;
            }
            float z = zarr[vn], dd = darr[vn];
            vis[nb][v] = 1.f - fabsf(z - dd) / (z + 1e-9f);
        }
    }
    __syncthreads();

    float h[NB][NV];
    float bv = b1[tid];
#pragma unroll
    for (int nb = 0; nb < NB; ++nb)
#pragma unroll
        for (int v = 0; v < NV; ++v) h[nb][v] = bv;
    for (int c = 0; c < NC; ++c) {
        float w = W1[c * NDH + tid];
#pragma unroll
        for (int nb = 0; nb < NB; ++nb)
#pragma unroll
            for (int v = 0; v < NV; ++v) h[nb][v] = fmaf(fs[nb][v][c], w, h[nb][v]);
    }
    {
        float w = W1[NC * NDH + tid];
#pragma unroll
        for (int nb = 0; nb < NB; ++nb)
#pragma unroll
            for (int v = 0; v < NV; ++v) h[nb][v] = fmaf(vis[nb][v], w, h[nb][v]);
    }
    float w2t = w2[tid];
    int lane = tid & 63, wave = tid >> 6;
#pragma unroll
    for (int nb = 0; nb < NB; ++nb) {
#pragma unroll
        for (int v = 0; v < NV; ++v) {
            float p = fmaxf(h[nb][v], 0.f) * w2t;
#pragma unroll
            for (int off = 32; off > 0; off >>= 1) p += __shfl_down(p, off);
            if (lane == 0) red[nb][v][wave] = p;
        }
    }
    __syncthreads();
    if (tid < NB * NV) {
        int nb = tid >> 2, v = tid & 3;
        sc[nb][v] = red[nb][v][0] + red[nb][v][1];
    }
    __syncthreads();
    if (tid < NB) {
        float s0 = sc[tid][0], s1 = sc[tid][1], s2 = sc[tid][2], s3 = sc[tid][3];
        float mx = fmaxf(fmaxf(s0, s1), fmaxf(s2, s3));
        float e0 = expf(s0 - mx), e1 = expf(s1 - mx);
        float e2 = expf(s2 - mx), e3 = expf(s3 - mx);
        float inv = 1.f / (e0 + e1 + e2 + e3);
        sc[tid][0] = e0 * inv; sc[tid][1] = e1 * inv;
        sc[tid][2] = e2 * inv; sc[tid][3] = e3 * inv;
    }
    __syncthreads();
#pragma unroll
    for (int nb = 0; nb < NB; ++nb) {
        int n = n0 + nb;
        float f = 0.f;
#pragma unroll
        for (int v = 0; v < NV; ++v) f += sc[nb][v] * fs[nb][v][tid];
        out[(size_t)n * OUTC + tid] = f;
        if (tid < 3) {
            float r = 0.f;
#pragma unroll
            for (int v = 0; v < NV; ++v) r += sc[nb][v] * rgbs[nb][v][tid];
            out[(size_t)n * OUTC + NC + tid] = r;
        }
    }
}

// ---------------------------------------------------------------------------
extern "C" void kernel_launch(void* const* d_in, const int* in_sizes, int n_in,
                              void* d_out, int out_size, void* d_ws, size_t ws_size,
                              hipStream_t stream) {
    const float* pts = (const float*)d_in[0];
    const float* extr = (const float*)d_in[1];
    const float* intr = (const float*)d_in[2];
    const float* zbuffer = (const float*)d_in[3];
    const float* feat = (const float*)d_in[4];
    const float* image = (const float*)d_in[5];
    const float* W1 = (const float*)d_in[6];
    const float* b1 = (const float*)d_in[7];
    const float* w2 = (const float*)d_in[8];
    float* out = (float*)d_out;

    const size_t VN = (size_t)NV * NPT;
    float* uarr = (float*)d_ws;
    float* varr = uarr + VN;
    float* darr = varr + VN;
    float* zarr = darr + VN;
    int* mask = (int*)(zarr + VN);              // NPT ints
    int* list = mask + NPT;                     // NPT ints
    int* counter = list + NPT;                  // 16 ints (aligned pad)
    char* after = (char*)(counter + 16);        // ~4.98 MB from base
    ushort16* trgb = (ushort16*)after;          // V*H*W*4 bf16 = 8 MB
    ushort16* tfeat = (ushort16*)(after + (size_t)NV * IMH * IMW * 4 * 2);  // 256 MB
    size_t need = (size_t)((char*)tfeat - (char*)d_ws) + (size_t)NV * IMH * IMW * NC * 2;

    int total = NV * NPT;
    k_zero<<<1, 1, 0, stream>>>(counter);
    k_project<<<(total + 255) / 256, 256, 0, stream>>>(pts, extr, intr, zbuffer,
                                                       uarr, varr, darr, zarr);
    k_mask<<<(NPT + 255) / 256, 256, 0, stream>>>(zarr, mask, list, counter);
    k_knn_c<<<NPT / 256, 256, 0, stream>>>(pts, mask, list, counter, zarr);

    if (ws_size >= need) {
        k_tfeat<<<NV * 512 * 4, 256, 0, stream>>>(feat, tfeat);
        k_trgb<<<NV * 512 * 2, 256, 0, stream>>>(image, trgb);
        k_fused_t<<<NPT / NB, 128, 0, stream>>>(uarr, varr, darr, zarr, tfeat, trgb,
                                                W1, b1, w2, out);
    } else {
        k_fused_d<<<NPT / NB, 128, 0, stream>>>(uarr, varr, darr, zarr, feat, image,
                                                W1, b1, w2, out);
    }
}

// Round 6
// 467.712 us; speedup vs baseline: 3.5331x; 1.2915x over previous
//
#include <hip/hip_runtime.h>
#include <math.h>

#define NV 4
#define NPT 65536
#define NC 128
#define IMH 512
#define IMW 512
#define MPOOL 1024
#define NDH 128
#define KNN 5
#define NB 4
#define OUTC 131

typedef unsigned int uint32;
typedef unsigned short ushort16;
typedef __attribute__((ext_vector_type(8))) short short8v;
typedef __attribute__((ext_vector_type(4))) float float4v;

__device__ inline ushort16 f2bf(float f) {           // round-to-nearest-even
    uint32 u = __float_as_uint(f);
    u += 0x7fffu + ((u >> 16) & 1u);
    return (ushort16)(u >> 16);
}
__device__ inline float bflo(uint32 a) { return __uint_as_float(a << 16); }
__device__ inline float bfhi(uint32 a) { return __uint_as_float(a & 0xffff0000u); }
__device__ inline float bf1(ushort16 a) { return __uint_as_float(((uint32)a) << 16); }

// ---------------------------------------------------------------------------
// W1 -> bf16 MFMA B-fragments (once, tiny). Also zeroes the compaction counter.
// Layout: Bf[(kb*8+t)*64 + lane] = 8 bf16 = B[k][d], d = t*16 + (lane&15),
//         k = kb*32 + (lane>>4)*8 + j  (zero-padded for k >= 129).
// ---------------------------------------------------------------------------
__global__ void k_wprep(const float* __restrict__ W1, uint4* __restrict__ Bf,
                        int* __restrict__ counter) {
    int idx = blockIdx.x * blockDim.x + threadIdx.x;
    if (idx == 0) *counter = 0;
    if (idx >= 5 * 8 * 64) return;
    int l = idx & 63, t = (idx >> 6) & 7, kb = idx >> 9;
    int d = t * 16 + (l & 15);
    uint32 w[4];
#pragma unroll
    for (int p = 0; p < 4; ++p) {
        uint32 lohi = 0;
#pragma unroll
        for (int h = 0; h < 2; ++h) {
            int j = p * 2 + h;
            int k = kb * 32 + (l >> 4) * 8 + j;
            float wv = (k < NC + 1) ? W1[k * NDH + d] : 0.f;
            lohi |= ((uint32)f2bf(wv)) << (16 * h);
        }
        w[p] = lohi;
    }
    Bf[idx] = make_uint4(w[0], w[1], w[2], w[3]);
}

// ---------------------------------------------------------------------------
// Fused project + zbuffer sample + mask + compaction. One thread per point.
// ---------------------------------------------------------------------------
__global__ __launch_bounds__(256)
void k_prep(const float* __restrict__ pts, const float* __restrict__ extr,
            const float* __restrict__ intr, const float* __restrict__ zbuffer,
            float* __restrict__ uarr, float* __restrict__ varr,
            float* __restrict__ darr, float* __restrict__ zarr,
            int* __restrict__ mask, int* __restrict__ list,
            int* __restrict__ counter) {
    int n = blockIdx.x * blockDim.x + threadIdx.x;
    if (n >= NPT) return;
    float p0 = pts[3 * n], p1 = pts[3 * n + 1], p2 = pts[3 * n + 2];
    int msk = 0;
#pragma unroll
    for (int v = 0; v < NV; ++v) {
        const float* e = extr + v * 12;
        float c0 = e[0] * p0 + e[1] * p1 + e[2] * p2 + e[3];
        float c1 = e[4] * p0 + e[5] * p1 + e[6] * p2 + e[7];
        float c2 = e[8] * p0 + e[9] * p1 + e[10] * p2 + e[11];
        const float* kk = intr + v * 9;
        float x0 = kk[0] * c0 + kk[1] * c1 + kk[2] * c2;
        float x1 = kk[3] * c0 + kk[4] * c1 + kk[5] * c2;
        float x2 = kk[6] * c0 + kk[7] * c1 + kk[8] * c2;
        float uu = x0 / (x2 + 1e-9f);
        float vv = x1 / (x2 + 1e-9f);
        int vn = v * NPT + n;
        uarr[vn] = uu; varr[vn] = vv; darr[vn] = c2;

        const float* img = zbuffer + (size_t)v * IMH * IMW;
        float u0f = floorf(uu), v0f = floorf(vv);
        float du = uu - u0f, dv = vv - v0f;
        int iu0 = (int)u0f, iv0 = (int)v0f;
        float w00 = (1.f - du) * (1.f - dv);
        float w01 = du * (1.f - dv);
        float w10 = (1.f - du) * dv;
        float w11 = du * dv;
        int iu0c = min(max(iu0, 0), IMW - 1), iu1c = min(max(iu0 + 1, 0), IMW - 1);
        int iv0c = min(max(iv0, 0), IMH - 1), iv1c = min(max(iv0 + 1, 0), IMH - 1);
        float m00 = (iu0 >= 0 && iu0 < IMW && iv0 >= 0 && iv0 < IMH) ? w00 : 0.f;
        float m01 = (iu0 + 1 >= 0 && iu0 + 1 < IMW && iv0 >= 0 && iv0 < IMH) ? w01 : 0.f;
        float m10 = (iu0 >= 0 && iu0 < IMW && iv0 + 1 >= 0 && iv0 + 1 < IMH) ? w10 : 0.f;
        float m11 = (iu0 + 1 >= 0 && iu0 + 1 < IMW && iv0 + 1 >= 0 && iv0 + 1 < IMH) ? w11 : 0.f;
        float z = img[iv0c * IMW + iu0c] * m00 + img[iv0c * IMW + iu1c] * m01 +
                  img[iv1c * IMW + iu0c] * m10 + img[iv1c * IMW + iu1c] * m11;
        zarr[vn] = z;
        msk |= (z == 0.f);
    }
    mask[n] = msk;
    if (msk) {
        int pos = atomicAdd(counter, 1);   // compiler coalesces per-wave
        list[pos] = n;
    }
}

// ---------------------------------------------------------------------------
// Dense KNN over compacted masked points; candidates staged in LDS.
// ---------------------------------------------------------------------------
__global__ __launch_bounds__(256)
void k_knn_c(const float* __restrict__ pts, const int* __restrict__ mask,
             const int* __restrict__ list, const int* __restrict__ counter,
             float* __restrict__ zarr) {
    __shared__ float cx[MPOOL], cy[MPOOL], cz[MPOOL];
    int count = *counter;
    if ((int)blockIdx.x * 256 >= count) return;
    for (int m = threadIdx.x; m < MPOOL; m += 256) {
        int bad = mask[m];
        cx[m] = bad ? INFINITY : pts[3 * m];
        cy[m] = pts[3 * m + 1];
        cz[m] = pts[3 * m + 2];
    }
    __syncthreads();
    int i = blockIdx.x * 256 + threadIdx.x;
    if (i >= count) return;
    int n = list[i];
    float px = pts[3 * n], py = pts[3 * n + 1], pz = pts[3 * n + 2];
    float bd[KNN];
    int bi[KNN];
#pragma unroll
    for (int k = 0; k < KNN; ++k) { bd[k] = INFINITY; bi[k] = 0; }
    for (int m = 0; m < MPOOL; ++m) {
        float dx = px - cx[m];
        float dy = py - cy[m];
        float dz = pz - cz[m];
        float d = dx * dx + dy * dy + dz * dz;   // INF for bad candidates
        int id = m;
#pragma unroll
        for (int k = 0; k < KNN; ++k) {
            if (d < bd[k]) {        // strict <: ties keep lower index (jax top_k)
                float td = bd[k]; int ti = bi[k];
                bd[k] = d; bi[k] = id;
                d = td; id = ti;
            }
        }
    }
    float disp[KNN];
    float s = 0.f;
#pragma unroll
    for (int k = 0; k < KNN; ++k) {
        float dist = sqrtf(fmaxf(bd[k], 0.f));
        disp[k] = 1.f / (dist + 1e-8f);
        s += disp[k];
    }
    float inv = 1.f / (s + 1e-12f);
#pragma unroll
    for (int v = 0; v < NV; ++v) {
        float r = 0.f;
#pragma unroll
        for (int k = 0; k < KNN; ++k) r += zarr[v * NPT + bi[k]] * (disp[k] * inv);
        zarr[v * NPT + n] = r;
    }
}

// ---------------------------------------------------------------------------
// Transpose feat [V,C,H,W] f32 -> tfeat [V,H,W,C] bf16. 128 pix x 128 ch tile.
// ---------------------------------------------------------------------------
__global__ __launch_bounds__(256)
void k_tfeat(const float* __restrict__ feat, ushort16* __restrict__ tfeat) {
    __shared__ ushort16 tile[128][130];
    int bid = blockIdx.x;
    int xt = bid & 3;
    int y = (bid >> 2) & 511;
    int v = bid >> 11;
    int x0 = xt * 128;
    int lane = threadIdx.x & 63, wave = threadIdx.x >> 6;
    const size_t HW = (size_t)IMH * IMW;
    const float* src = feat + (size_t)v * NC * HW + (size_t)y * IMW + x0;
#pragma unroll
    for (int i = 0; i < 32; ++i) {
        int c = i * 4 + wave;
        float2 val = *(const float2*)(src + (size_t)c * HW + lane * 2);
        tile[lane * 2][c] = f2bf(val.x);
        tile[lane * 2 + 1][c] = f2bf(val.y);
    }
    __syncthreads();
    uint32* dst = (uint32*)tfeat + ((size_t)v * HW + (size_t)y * IMW + x0) * 64;
#pragma unroll
    for (int i = 0; i < 32; ++i) {
        int pix = i * 4 + wave;
        uint32 val = *(const uint32*)&tile[pix][2 * lane];
        dst[(size_t)pix * 64 + lane] = val;
    }
}

// ---------------------------------------------------------------------------
// Transpose image [V,3,H,W] f32 -> trgb [V,H,W,4] bf16
// ---------------------------------------------------------------------------
__global__ __launch_bounds__(256)
void k_trgb(const float* __restrict__ image, ushort16* __restrict__ trgb) {
    int bid = blockIdx.x;
    int xt = bid & 1, y = (bid >> 1) & 511, v = bid >> 10;
    int x = xt * 256 + threadIdx.x;
    const size_t HW = (size_t)IMH * IMW;
    size_t p = (size_t)y * IMW + x;
    const float* src = image + (size_t)v * 3 * HW;
    ushort4 o;
    o.x = f2bf(src[p]);
    o.y = f2bf(src[HW + p]);
    o.z = f2bf(src[2 * HW + p]);
    o.w = 0;
    *(ushort4*)(trgb + ((size_t)v * HW + p) * 4) = o;
}

// ---------------------------------------------------------------------------
// Fused sampling + MFMA MLP + softmax + blend.
// Block 128 threads = 2 waves, NB=4 points x 4 views (q in [0,16)).
// x matrix: [16 q][160 k] bf16 in LDS (k: 128 feat + vis + zero pad).
// MLP: D[16 q][128 d] = x . W1  via mfma_f32_16x16x32_bf16, wave w owns
// d-tiles t = 4w..4w+3. C/D layout: col=lane&15 (d), row=(lane>>4)*4+reg (q).
// ---------------------------------------------------------------------------
__global__ __launch_bounds__(128)
void k_fused_m(const float* __restrict__ uarr, const float* __restrict__ varr,
               const float* __restrict__ darr, const float* __restrict__ zarr,
               const ushort16* __restrict__ tfeat, const ushort16* __restrict__ trgb,
               const uint4* __restrict__ Bf, const float* __restrict__ b1,
               const float* __restrict__ w2, float* __restrict__ out) {
    const int tid = threadIdx.x;
    const int n0 = blockIdx.x * NB;
    const size_t HW = (size_t)IMH * IMW;
    __shared__ ushort16 fs[16][168];      // row stride 336 B (16B-aligned, 2-way banks)
    __shared__ float rgbs[16][3];
    __shared__ int po[16][4];
    __shared__ float pm[16][4];
    __shared__ float viss[16];
    __shared__ float sc[16];
    __shared__ float red[16][2];

    if (tid < 16) {
        int nb = tid >> 2, v = tid & 3;
        int vn = v * NPT + n0 + nb;
        float uu = uarr[vn], vv = varr[vn];
        float u0f = floorf(uu), v0f = floorf(vv);
        float du = uu - u0f, dv = vv - v0f;
        int iu0 = (int)u0f, iv0 = (int)v0f;
        float w00 = (1.f - du) * (1.f - dv);
        float w01 = du * (1.f - dv);
        float w10 = (1.f - du) * dv;
        float w11 = du * dv;
        int iu0c = min(max(iu0, 0), IMW - 1), iu1c = min(max(iu0 + 1, 0), IMW - 1);
        int iv0c = min(max(iv0, 0), IMH - 1), iv1c = min(max(iv0 + 1, 0), IMH - 1);
        float m00 = (iu0 >= 0 && iu0 < IMW && iv0 >= 0 && iv0 < IMH) ? w00 : 0.f;
        float m01 = (iu0 + 1 < IMW && iu0 + 1 >= 0 && iv0 >= 0 && iv0 < IMH) ? w01 : 0.f;
        float m10 = (iu0 >= 0 && iu0 < IMW && iv0 + 1 < IMH && iv0 + 1 >= 0) ? w10 : 0.f;
        float m11 = (iu0 + 1 < IMW && iu0 + 1 >= 0 && iv0 + 1 < IMH && iv0 + 1 >= 0) ? w11 : 0.f;
        int o00 = iv0c * IMW + iu0c, o01 = iv0c * IMW + iu1c;
        int o10 = iv1c * IMW + iu0c, o11 = iv1c * IMW + iu1c;
        po[tid][0] = o00; po[tid][1] = o01; po[tid][2] = o10; po[tid][3] = o11;
        pm[tid][0] = m00; pm[tid][1] = m01; pm[tid][2] = m10; pm[tid][3] = m11;
        float z = zarr[vn], dd = darr[vn];
        float vis = 1.f - fabsf(z - dd) / (z + 1e-9f);
        viss[tid] = vis;
        fs[tid][128] = f2bf(vis);                 // k=128 row of x
        for (int k = 129; k < 168; ++k) fs[tid][k] = 0;
        // rgb bilinear (bf16 [pix][4])
        const ushort16* rb = trgb + (size_t)v * HW * 4;
        float ar = 0.f, ag = 0.f, ab = 0.f;
        int oo[4] = {o00, o01, o10, o11};
        float mm[4] = {m00, m01, m10, m11};
#pragma unroll
        for (int k = 0; k < 4; ++k) {
            const ushort16* c = rb + (size_t)oo[k] * 4;
            ar += bf1(c[0]) * mm[k];
            ag += bf1(c[1]) * mm[k];
            ab += bf1(c[2]) * mm[k];
        }
        rgbs[tid][0] = ar; rgbs[tid][1] = ag; rgbs[tid][2] = ab;
    }
    __syncthreads();

    // sampling: half-wave per q; lane = channel pair; pack to bf16 x-matrix
    const uint32* T = (const uint32*)tfeat;
    int sub = tid >> 6, c2 = tid & 63;
#pragma unroll
    for (int i = 0; i < 8; ++i) {
        int q = i * 2 + sub;
        int v = q & 3;
        const uint32* Bv = T + (size_t)v * HW * 64;
        int o0 = po[q][0], o1 = po[q][1], o2 = po[q][2], o3 = po[q][3];
        float m0 = pm[q][0], m1 = pm[q][1], m2 = pm[q][2], m3 = pm[q][3];
        uint32 a0 = Bv[(size_t)o0 * 64 + c2];
        uint32 a1 = Bv[(size_t)o1 * 64 + c2];
        uint32 a2 = Bv[(size_t)o2 * 64 + c2];
        uint32 a3 = Bv[(size_t)o3 * 64 + c2];
        float lo = bflo(a0) * m0 + bflo(a1) * m1 + bflo(a2) * m2 + bflo(a3) * m3;
        float hi = bfhi(a0) * m0 + bfhi(a1) * m1 + bfhi(a2) * m2 + bfhi(a3) * m3;
        uint32 packed = (uint32)f2bf(lo) | ((uint32)f2bf(hi) << 16);
        *(uint32*)&fs[q][2 * c2] = packed;
    }
    __syncthreads();

    // MFMA MLP: h[16 q][128 d] += x . W1; wave w handles d-tiles 4w..4w+3
    const int l = tid & 63, w = tid >> 6;
    const int mrow = l & 15, kg = l >> 4;
    float4v acc[4];
#pragma unroll
    for (int t = 0; t < 4; ++t) acc[t] = (float4v){0.f, 0.f, 0.f, 0.f};
#pragma unroll
    for (int kb = 0; kb < 5; ++kb) {
        short8v av = *(const short8v*)&fs[mrow][kb * 32 + kg * 8];
#pragma unroll
        for (int tt = 0; tt < 4; ++tt) {
            int t = w * 4 + tt;
            short8v bv = *(const short8v*)&Bf[(kb * 8 + t) * 64 + l];
            acc[tt] = __builtin_amdgcn_mfma_f32_16x16x32_bf16(av, bv, acc[tt], 0, 0, 0);
        }
    }
    // score partials: p[r] = sum_d relu(h + b1) * w2 over this lane's d's
    float bias[4], w2v[4];
#pragma unroll
    for (int tt = 0; tt < 4; ++tt) {
        int d = (w * 4 + tt) * 16 + mrow;
        bias[tt] = b1[d];
        w2v[tt] = w2[d];
    }
    float p[4] = {0.f, 0.f, 0.f, 0.f};
#pragma unroll
    for (int tt = 0; tt < 4; ++tt)
#pragma unroll
        for (int r = 0; r < 4; ++r)
            p[r] += fmaxf(acc[tt][r] + bias[tt], 0.f) * w2v[tt];
#pragma unroll
    for (int m = 1; m < 16; m <<= 1)
#pragma unroll
        for (int r = 0; r < 4; ++r) p[r] += __shfl_xor(p[r], m);
    if (mrow == 0) {
#pragma unroll
        for (int r = 0; r < 4; ++r) red[kg * 4 + r][w] = p[r];
    }
    __syncthreads();
    if (tid < 16) sc[tid] = red[tid][0] + red[tid][1];
    __syncthreads();
    if (tid < NB) {
        float s0 = sc[tid * 4 + 0], s1 = sc[tid * 4 + 1];
        float s2 = sc[tid * 4 + 2], s3 = sc[tid * 4 + 3];
        float mx = fmaxf(fmaxf(s0, s1), fmaxf(s2, s3));
        float e0 = expf(s0 - mx), e1 = expf(s1 - mx);
        float e2 = expf(s2 - mx), e3 = expf(s3 - mx);
        float inv = 1.f / (e0 + e1 + e2 + e3);
        sc[tid * 4 + 0] = e0 * inv; sc[tid * 4 + 1] = e1 * inv;
        sc[tid * 4 + 2] = e2 * inv; sc[tid * 4 + 3] = e3 * inv;
    }
    __syncthreads();

#pragma unroll
    for (int nb = 0; nb < NB; ++nb) {
        int n = n0 + nb;
        float f = 0.f;
#pragma unroll
        for (int v = 0; v < NV; ++v) f += sc[nb * 4 + v] * bf1(fs[nb * 4 + v][tid]);
        out[(size_t)n * OUTC + tid] = f;
        if (tid < 3) {
            float r = 0.f;
#pragma unroll
            for (int v = 0; v < NV; ++v) r += sc[nb * 4 + v] * rgbs[nb * 4 + v][tid];
            out[(size_t)n * OUTC + NC + tid] = r;
        }
    }
}

// ---------------------------------------------------------------------------
// Fallback fused kernel (direct [V,C,H,W] reads) — used only if ws too small.
// ---------------------------------------------------------------------------
__global__ __launch_bounds__(128)
void k_fused_d(const float* __restrict__ uarr, const float* __restrict__ varr,
               const float* __restrict__ darr, const float* __restrict__ zarr,
               const float* __restrict__ feat, const float* __restrict__ image,
               const float* __restrict__ W1, const float* __restrict__ b1,
               const float* __restrict__ w2, float* __restrict__ out) {
    const int tid = threadIdx.x;
    const int n0 = blockIdx.x * NB;
    __shared__ float fs[NB][NV][NC];
    __shared__ float rgbs[NB][NV][3];
    __shared__ float sc[NB][NV];
    __shared__ float red[NB][NV][2];
    float vis[NB][NV];

#pragma unroll
    for (int nb = 0; nb < NB; ++nb) {
        int n = n0 + nb;
#pragma unroll
        for (int v = 0; v < NV; ++v) {
            int vn = v * NPT + n;
            float uu = uarr[vn], vv = varr[vn];
            float u0f = floorf(uu), v0f = floorf(vv);
            float du = uu - u0f, dv = vv - v0f;
            int iu0 = (int)u0f, iv0 = (int)v0f;
            float w00 = (1.f - du) * (1.f - dv);
            float w01 = du * (1.f - dv);
            float w10 = (1.f - du) * dv;
            float w11 = du * dv;
            int iu0c = min(max(iu0, 0), IMW - 1), iu1c = min(max(iu0 + 1, 0), IMW - 1);
            int iv0c = min(max(iv0, 0), IMH - 1), iv1c = min(max(iv0 + 1, 0), IMH - 1);
            float m00 = (iu0 >= 0 && iu0 < IMW && iv0 >= 0 && iv0 < IMH) ? w00 : 0.f;
            float m01 = (iu0 + 1 < IMW && iu0 + 1 >= 0 && iv0 >= 0 && iv0 < IMH) ? w01 : 0.f;
            float m10 = (iu0 >= 0 && iu0 < IMW && iv0 + 1 < IMH && iv0 + 1 >= 0) ? w10 : 0.f;
            float m11 = (iu0 + 1 < IMW && iu0 + 1 >= 0 && iv0 + 1 < IMH && iv0 + 1 >= 0) ? w11 : 0.f;
            int o00 = iv0c * IMW + iu0c, o01 = iv0c * IMW + iu1c;
            int o10 = iv1c * IMW + iu0c, o11 = iv1c * IMW + iu1c;
            const float* base = feat + ((size_t)(v * NC + tid)) * IMH * IMW;
            fs[nb][v][tid] = base[o00] * m00 + base[o01] * m01 +
                             base[o10] * m10 + base[o11] * m11;
            if (tid < 3) {
                const float* ib = image + ((size_t)(v * 3 + tid)) * IMH * IMW;
                rgbs[nb][v][tid] = ib[o00] * m00 + ib[o01] * m01 +
                                   ib[o10] * m10 + ib[o11] * m11;
            }
            float z = zarr[vn], dd = darr[vn];
            vis[nb][v] = 1.f - fabsf(z - dd) / (z + 1e-9f);
        }
    }
    __syncthreads();

    float h[NB][NV];
    float bv = b1[tid];
#pragma unroll
    for (int nb = 0; nb < NB; ++nb)
#pragma unroll
        for (int v = 0; v < NV; ++v) h[nb][v] = bv;
    for (int c = 0; c < NC; ++c) {
        float w = W1[c * NDH + tid];
#pragma unroll
        for (int nb = 0; nb < NB; ++nb)
#pragma unroll
            for (int v = 0; v < NV; ++v) h[nb][v] = fmaf(fs[nb][v][c], w, h[nb][v]);
    }
    {
        float w = W1[NC * NDH + tid];
#pragma unroll
        for (int nb = 0; nb < NB; ++nb)
#pragma unroll
            for (int v = 0; v < NV; ++v) h[nb][v] = fmaf(vis[nb][v], w, h[nb][v]);
    }
    float w2t = w2[tid];
    int lane = tid & 63, wave = tid >> 6;
#pragma unroll
    for (int nb = 0; nb < NB; ++nb) {
#pragma unroll
        for (int v = 0; v < NV; ++v) {
            float p = fmaxf(h[nb][v], 0.f) * w2t;
#pragma unroll
            for (int off = 32; off > 0; off >>= 1) p += __shfl_down(p, off);
            if (lane == 0) red[nb][v][wave] = p;
        }
    }
    __syncthreads();
    if (tid < NB * NV) {
        int nb = tid >> 2, v = tid & 3;
        sc[nb][v] = red[nb][v][0] + red[nb][v][1];
    }
    __syncthreads();
    if (tid < NB) {
        float s0 = sc[tid][0], s1 = sc[tid][1], s2 = sc[tid][2], s3 = sc[tid][3];
        float mx = fmaxf(fmaxf(s0, s1), fmaxf(s2, s3));
        float e0 = expf(s0 - mx), e1 = expf(s1 - mx);
        float e2 = expf(s2 - mx), e3 = expf(s3 - mx);
        float inv = 1.f / (e0 + e1 + e2 + e3);
        sc[tid][0] = e0 * inv; sc[tid][1] = e1 * inv;
        sc[tid][2] = e2 * inv; sc[tid][3] = e3 * inv;
    }
    __syncthreads();
#pragma unroll
    for (int nb = 0; nb < NB; ++nb) {
        int n = n0 + nb;
        float f = 0.f;
#pragma unroll
        for (int v = 0; v < NV; ++v) f += sc[nb][v] * fs[nb][v][tid];
        out[(size_t)n * OUTC + tid] = f;
        if (tid < 3) {
            float r = 0.f;
#pragma unroll
            for (int v = 0; v < NV; ++v) r += sc[nb][v] * rgbs[nb][v][tid];
            out[(size_t)n * OUTC + NC + tid] = r;
        }
    }
}

// ---------------------------------------------------------------------------
extern "C" void kernel_launch(void* const* d_in, const int* in_sizes, int n_in,
                              void* d_out, int out_size, void* d_ws, size_t ws_size,
                              hipStream_t stream) {
    const float* pts = (const float*)d_in[0];
    const float* extr = (const float*)d_in[1];
    const float* intr = (const float*)d_in[2];
    const float* zbuffer = (const float*)d_in[3];
    const float* feat = (const float*)d_in[4];
    const float* image = (const float*)d_in[5];
    const float* W1 = (const float*)d_in[6];
    const float* b1 = (const float*)d_in[7];
    const float* w2 = (const float*)d_in[8];
    float* out = (float*)d_out;

    const size_t VN = (size_t)NV * NPT;
    float* uarr = (float*)d_ws;
    float* varr = uarr + VN;
    float* darr = varr + VN;
    float* zarr = darr + VN;
    int* mask = (int*)(zarr + VN);              // NPT ints
    int* list = mask + NPT;                     // NPT ints
    int* counter = list + NPT;                  // 16 ints
    uint4* Bf = (uint4*)(counter + 16);         // 5*8*64 uint4 = 40 KB
    char* after = (char*)(Bf + 5 * 8 * 64);
    ushort16* trgb = (ushort16*)after;          // V*H*W*4 bf16 = 8 MB
    ushort16* tfeat = (ushort16*)(after + (size_t)NV * IMH * IMW * 4 * 2);  // 256 MB
    size_t need = (size_t)((char*)tfeat - (char*)d_ws) + (size_t)NV * IMH * IMW * NC * 2;

    k_wprep<<<10, 256, 0, stream>>>(W1, Bf, counter);
    k_prep<<<NPT / 256, 256, 0, stream>>>(pts, extr, intr, zbuffer,
                                          uarr, varr, darr, zarr,
                                          mask, list, counter);
    k_knn_c<<<NPT / 256, 256, 0, stream>>>(pts, mask, list, counter, zarr);

    if (ws_size >= need) {
        k_tfeat<<<NV * 512 * 4, 256, 0, stream>>>(feat, tfeat);
        k_trgb<<<NV * 512 * 2, 256, 0, stream>>>(image, trgb);
        k_fused_m<<<NPT / NB, 128, 0, stream>>>(uarr, varr, darr, zarr, tfeat, trgb,
                                                Bf, b1, w2, out);
    } else {
        k_fused_d<<<NPT / NB, 128, 0, stream>>>(uarr, varr, darr, zarr, feat, image,
                                                W1, b1, w2, out);
    }
}